// Round 2
// baseline (428.654 us; speedup 1.0000x reference)
//
#include <hip/hip_runtime.h>

#define BB 8
#define SS 4096
#define HIDD 1024
#define HH 16
#define DHH 64

// K1: weff[o][i], o<16: sum_d aw[o,d]*Wq[o*64+d, i]; o>=16: same with Wk.
// wq_f and wk_f are adjacent in ws => weff = wq_f is [32][1024].
// grid (4, 16, 2), block 256
__global__ __launch_bounds__(256) void k_prep(const float* __restrict__ Wq,
                                              const float* __restrict__ Wk,
                                              const float* __restrict__ aw,
                                              float* __restrict__ wq_f,
                                              float* __restrict__ wk_f) {
    int i = blockIdx.x * 256 + threadIdx.x;
    int h = blockIdx.y;
    const float* W = blockIdx.z ? Wk : Wq;
    float* outp = blockIdx.z ? wk_f : wq_f;
    float acc = 0.f;
#pragma unroll
    for (int d = 0; d < DHH; ++d) {
        acc += aw[h * DHH + d] * W[(size_t)(h * DHH + d) * HIDD + i];
    }
    outp[h * HIDD + i] = acc;
}

// K2 v5: tall-skinny GEMM  scores[32768 rows][32 outs] = hid x weff^T.
// Single pass again (hid fetched ONCE): block 256 = 4 waves, 64 rows/block,
// wave og owns outs og*8..og*8+7. grid 512.
// LDS stride 132 floats: lane*132*4 = lane*528 is 16B-aligned -> ONE
// ds_read_b128 per k-step (was 4x ds_read_b32 at stride 129). Start banks
// 4*(lane+c)%32: 8 lanes per 4-bank group, perfectly balanced -> conflict-free
// at the 128B/cyc LDS ceiling. Staging uses ds_write_b128 likewise.
// Register double-buffer prefetch of next chunk kept from v4.
#define KC 128
#define LSTR 132
__global__ __launch_bounds__(256, 4) void k_scores(const float* __restrict__ hid,
                                                   const float* __restrict__ mask,
                                                   const float* __restrict__ weff,
                                                   float* __restrict__ qsb,
                                                   float* __restrict__ ksb) {
    __shared__ float sh[64 * LSTR];   // 33792 floats = 33 KB -> 4 blocks/CU

    const int t    = threadIdx.x;
    const int wave = t >> 6;
    const int lane = t & 63;
    const int obase = __builtin_amdgcn_readfirstlane(wave * 8);

    const int row  = blockIdx.x * 64 + lane;       // global row (b*4096+s)
    const size_t gbase = (size_t)blockIdx.x * 64 * HIDD;

    float acc[8];
#pragma unroll
    for (int o = 0; o < 8; ++o) acc[o] = 0.f;

    float4 stg[8];
#pragma unroll
    for (int j = 0; j < 8; ++j) {
        int f  = j * 256 + t;
        int r  = f >> 5;           // 32 float4 per row
        int c4 = f & 31;
        stg[j] = *reinterpret_cast<const float4*>(
            hid + gbase + (size_t)r * HIDD + c4 * 4);
    }

    for (int chunk = 0; chunk < HIDD / KC; ++chunk) {
        __syncthreads();                    // prev compute done; LDS free
#pragma unroll
        for (int j = 0; j < 8; ++j) {
            int f  = j * 256 + t;
            int r  = f >> 5;
            int c4 = f & 31;
            *reinterpret_cast<float4*>(sh + r * LSTR + c4 * 4) = stg[j];
        }
        __syncthreads();                    // LDS ready
        if (chunk + 1 < HIDD / KC) {        // prefetch next chunk under compute
#pragma unroll
            for (int j = 0; j < 8; ++j) {
                int f  = j * 256 + t;
                int r  = f >> 5;
                int c4 = f & 31;
                stg[j] = *reinterpret_cast<const float4*>(
                    hid + gbase + (size_t)r * HIDD + (chunk + 1) * KC + c4 * 4);
            }
        }

        const float* wc = weff + chunk * KC;
#pragma unroll 8
        for (int k = 0; k < KC; k += 4) {
            float4 h4 = *reinterpret_cast<const float4*>(sh + lane * LSTR + k);
#pragma unroll
            for (int o = 0; o < 8; ++o) {
                float4 wv = *reinterpret_cast<const float4*>(
                    wc + (size_t)(obase + o) * HIDD + k);
                acc[o] += h4.x * wv.x + h4.y * wv.y + h4.z * wv.z + h4.w * wv.w;
            }
        }
    }

    float m = mask[row];               // mask is (B,1,1,S) = flat 32768
#pragma unroll
    for (int o = 0; o < 8; ++o) acc[o] *= m;

    float4 v0 = make_float4(acc[0], acc[1], acc[2], acc[3]);
    float4 v1 = make_float4(acc[4], acc[5], acc[6], acc[7]);
    if (obase < 16) {
        float4* p = reinterpret_cast<float4*>(qsb + (size_t)row * 16 + obase);
        p[0] = v0; p[1] = v1;
    } else {
        float4* p = reinterpret_cast<float4*>(ksb + (size_t)row * 20 + (obase - 16));
        p[0] = v0; p[1] = v1;
        if (obase == 16) ksb[(size_t)row * 20 + 16] = m;
    }
}

// K3 v3: NO atomics. Thread owns 4 cols (float4 loads, 68 accumulators),
// s-chunk 64 rows -> grid (64, 8) = 512 blocks = 2/CU.
// part[schunk][b][17][1024]: ksh partial (16 ch) + hsum partial (mask ch).
__global__ __launch_bounds__(256) void k_ksh(const float* __restrict__ hid,
                                             const float* __restrict__ ksb,
                                             float* __restrict__ part) {
    int b  = blockIdx.y;
    int i  = threadIdx.x * 4;
    int s0 = blockIdx.x * 64;

    float4 acc[17];
#pragma unroll
    for (int c = 0; c < 17; ++c) acc[c] = make_float4(0.f, 0.f, 0.f, 0.f);

    const float* hb = hid + (size_t)(b * SS + s0) * HIDD + i;
    const float* sb = ksb + (size_t)(b * SS + s0) * 20;

#pragma unroll 4
    for (int s = 0; s < 64; ++s) {
        float4 hv = *reinterpret_cast<const float4*>(hb + (size_t)s * HIDD);
        const float* sc = sb + s * 20;
#pragma unroll
        for (int c = 0; c < 17; ++c) {
            float scv = sc[c];
            acc[c].x += scv * hv.x;
            acc[c].y += scv * hv.y;
            acc[c].z += scv * hv.z;
            acc[c].w += scv * hv.w;
        }
    }

    float* pb = part + (((size_t)blockIdx.x * 8 + b) * 17) * 1024 + i;
#pragma unroll
    for (int c = 0; c < 17; ++c) {
        *reinterpret_cast<float4*>(pb + c * 1024) = acc[c];
    }
}

// K3b: reduce 64 schunk partials -> ksh[b][16][1024], hsum[b][1024].
// grid 544, block 256 (544*256 = 8*17*1024 outputs exactly)
__global__ __launch_bounds__(256) void k_red(const float* __restrict__ part,
                                             float* __restrict__ ksh,
                                             float* __restrict__ hsum) {
    int gid = blockIdx.x * 256 + threadIdx.x;
    int b = gid / 17408;               // 17*1024
    int r = gid - b * 17408;
    int c = r >> 10;
    int i = r & 1023;

    float s = 0.f;
#pragma unroll 8
    for (int k = 0; k < 64; ++k)
        s += part[(((size_t)k * 8 + b) * 17 + c) * 1024 + i];

    if (c < 16) ksh[((size_t)b * 16 + c) * 1024 + i] = s;
    else        hsum[b * 1024 + i] = s;
}

// K4 v2: mvn[b,j] = (Wv[j,:]·hsum[b,:])/len;  kvn[b,j] = (Wv[j,:]·ksh[b,j/64,:])/len
// grid (8, 32), block 256: 32 j per block, 8 lanes split each 1024-dot,
// __shfl_xor reduce over the 8-lane group.
__global__ __launch_bounds__(256) void k_fin(const float* __restrict__ Wv,
                                             const float* __restrict__ mask,
                                             const float* __restrict__ hsum,
                                             const float* __restrict__ ksh,
                                             float* __restrict__ mvn,
                                             float* __restrict__ kvn) {
    int b  = blockIdx.x;
    int j  = blockIdx.y * 32 + (threadIdx.x >> 3);
    int sl = threadIdx.x & 7;

    __shared__ float red[256];
    float lsum = 0.f;
    for (int s = threadIdx.x; s < SS; s += 256) lsum += mask[b * SS + s];
    red[threadIdx.x] = lsum;
    __syncthreads();
    for (int off = 128; off; off >>= 1) {
        if (threadIdx.x < off) red[threadIdx.x] += red[threadIdx.x + off];
        __syncthreads();
    }
    float invlen = 1.0f / red[0];

    int h = j >> 6;
    const float4* w4 = reinterpret_cast<const float4*>(Wv + (size_t)j * HIDD + sl * 128);
    const float4* hv = reinterpret_cast<const float4*>(hsum + b * HIDD + sl * 128);
    const float4* kv = reinterpret_cast<const float4*>(ksh + ((size_t)b * 16 + h) * HIDD + sl * 128);

    float mv = 0.f, kvv = 0.f;
#pragma unroll
    for (int c = 0; c < 32; ++c) {
        float4 w = w4[c], a = hv[c], k2 = kv[c];
        mv  += w.x * a.x  + w.y * a.y  + w.z * a.z  + w.w * a.w;
        kvv += w.x * k2.x + w.y * k2.y + w.z * k2.z + w.w * k2.w;
    }
#pragma unroll
    for (int off = 1; off < 8; off <<= 1) {
        mv  += __shfl_xor(mv, off);
        kvv += __shfl_xor(kvv, off);
    }
    if (sl == 0) {
        mvn[b * HIDD + j] = mv * invlen;
        kvn[b * HIDD + j] = kvv * invlen;
    }
}

// K5: out[b,s,j] = q_score[b,s,j/64]*mvn[b,j] + kvn[b,j], float4 stores.
// grid 16384, block 256, 8 elems/thread
__global__ __launch_bounds__(256) void k_out(const float* __restrict__ qsb,
                                             const float* __restrict__ mvn,
                                             const float* __restrict__ kvn,
                                             float* __restrict__ outp) {
    size_t e0 = ((size_t)blockIdx.x * 256 + threadIdx.x) * 8;
    int b   = (int)(e0 >> 22);                 // 4096*1024 = 2^22
    int rem = (int)(e0 & ((1u << 22) - 1));
    int s   = rem >> 10;
    int j   = rem & 1023;

    float q = qsb[(size_t)(b * SS + s) * 16 + (j >> 6)];
    const float4* mv4 = reinterpret_cast<const float4*>(mvn + b * HIDD + j);
    const float4* kv4 = reinterpret_cast<const float4*>(kvn + b * HIDD + j);
    float4 m0 = mv4[0], m1 = mv4[1];
    float4 k0 = kv4[0], k1 = kv4[1];

    float4 o0, o1;
    o0.x = q * m0.x + k0.x;  o0.y = q * m0.y + k0.y;
    o0.z = q * m0.z + k0.z;  o0.w = q * m0.w + k0.w;
    o1.x = q * m1.x + k1.x;  o1.y = q * m1.y + k1.y;
    o1.z = q * m1.z + k1.z;  o1.w = q * m1.w + k1.w;

    float4* op = reinterpret_cast<float4*>(outp + e0);
    op[0] = o0;
    op[1] = o1;
}

extern "C" void kernel_launch(void* const* d_in, const int* in_sizes, int n_in,
                              void* d_out, int out_size, void* d_ws, size_t ws_size,
                              hipStream_t stream) {
    const float* hid  = (const float*)d_in[0];   // (B,S,HID)
    const float* mask = (const float*)d_in[1];   // (B,1,1,S)
    const float* Wq   = (const float*)d_in[2];   // (HID,HID)
    const float* Wk   = (const float*)d_in[3];
    const float* Wv   = (const float*)d_in[4];
    const float* aw   = (const float*)d_in[5];   // (H,1,DH)
    float* outp = (float*)d_out;

    float* ws   = (float*)d_ws;
    float* wq_f = ws;                       // 16384   } weff[32][1024]
    float* wk_f = wq_f + 16384;             // 16384   } (adjacent)
    float* qsb  = wk_f + 16384;             // 8*4096*16 = 524288
    float* ksb  = qsb + 524288;             // 8*4096*20 = 655360
    float* ksh  = ksb + 655360;             // 8*16*1024 = 131072
    float* hsum = ksh + 131072;             // 8*1024   = 8192
    float* mvn  = hsum + 8192;              // 8192
    float* kvn  = mvn + 8192;               // 8192
    float* part = kvn + 8192;               // 64*8*17*1024 = 8912896 (~35.7 MB)
                                            // total ws ~41 MB

    k_prep  <<<dim3(4, 16, 2), 256, 0, stream>>>(Wq, Wk, aw, wq_f, wk_f);
    k_scores<<<dim3(512),      256, 0, stream>>>(hid, mask, wq_f, qsb, ksb);
    k_ksh   <<<dim3(64, 8),    256, 0, stream>>>(hid, ksb, part);
    k_red   <<<dim3(544),      256, 0, stream>>>(part, ksh, hsum);
    k_fin   <<<dim3(8, 32),    256, 0, stream>>>(Wv, mask, hsum, ksh, mvn, kvn);
    k_out   <<<dim3(16384),    256, 0, stream>>>(qsb, mvn, kvn, outp);
}

// Round 3
// 350.705 us; speedup vs baseline: 1.2223x; 1.2223x over previous
//
#include <hip/hip_runtime.h>

#define BB 8
#define SS 4096
#define HIDD 1024
#define HH 16
#define DHH 64

// K1: weff[o][i], o<16: sum_d aw[o,d]*Wq[o*64+d, i]; o>=16: same with Wk.
// wq_f and wk_f are adjacent in ws => weff = wq_f is [32][1024].
// grid (4, 16, 2), block 256
__global__ __launch_bounds__(256) void k_prep(const float* __restrict__ Wq,
                                              const float* __restrict__ Wk,
                                              const float* __restrict__ aw,
                                              float* __restrict__ wq_f,
                                              float* __restrict__ wk_f) {
    int i = blockIdx.x * 256 + threadIdx.x;
    int h = blockIdx.y;
    const float* W = blockIdx.z ? Wk : Wq;
    float* outp = blockIdx.z ? wk_f : wq_f;
    float acc = 0.f;
#pragma unroll
    for (int d = 0; d < DHH; ++d) {
        acc += aw[h * DHH + d] * W[(size_t)(h * DHH + d) * HIDD + i];
    }
    outp[h * HIDD + i] = acc;
}

// K2 v6: tall-skinny GEMM  scores[32768 rows][32 outs] = hid x weff^T.
// Block 512 thr = 8 waves, 64 rows/block, wave owns 4 outs (w*4). Grid 512.
// Staging: __builtin_amdgcn_global_load_lds width=16 into LINEAR double-buffered
// LDS [2][64][128] (2x32KB). No staging VGPRs -> no spill (round-2 bug: stg[]
// respilled 1KB/thread = 129MB WRITE_SIZE). Rule #21: linear LDS dest +
// inverse-swizzled global SOURCE (slot (r,c') holds col c'^(r&7)) + same XOR
// on the ds_read side: lane reads f4-col kc at slot kc^(lane&7) ->
// per-16-lane phase each 4-bank group hit by exactly 2 lanes = conflict-free.
// 2-phase pipeline: issue next-chunk loads, compute current, vmcnt(0)+barrier.
#define KC 128
__global__ __launch_bounds__(512) void k_scores(const float* __restrict__ hid,
                                                const float* __restrict__ mask,
                                                const float* __restrict__ weff,
                                                float* __restrict__ qsb,
                                                float* __restrict__ ksb) {
    __shared__ float sh[2][64 * KC];      // 64 KB total -> 2 blocks/CU

    const int t    = threadIdx.x;         // 0..511
    const int lane = t & 63;
    const int wave = t >> 6;              // 0..7
    const int obase = __builtin_amdgcn_readfirstlane(wave * 4);  // 0,4,..,28

    const int row  = blockIdx.x * 64 + lane;        // global row (b*4096+s)
    const size_t gbase = (size_t)blockIdx.x * 64 * HIDD;
    const int swz = lane & 7;

    float acc[4] = {0.f, 0.f, 0.f, 0.f};

    // stage one 64x128 chunk: 2048 float4 slots, 4 per thread.
    // slot f = j*512+t: r=f>>5, c'=f&31; source col c = c'^(r&7).
    // LDS dest is linear (wave-uniform base + lane*16, required by HW).
    auto stage = [&](int chunk, int buf) {
#pragma unroll
        for (int j = 0; j < 4; ++j) {
            int f  = j * 512 + t;
            int r  = f >> 5;
            int cp = f & 31;
            int c  = cp ^ (r & 7);
            const float* gp = hid + gbase + (size_t)r * HIDD + chunk * KC + c * 4;
            float* lp = &sh[buf][f * 4];
            __builtin_amdgcn_global_load_lds(
                (const __attribute__((address_space(1))) void*)gp,
                (__attribute__((address_space(3))) void*)lp, 16, 0, 0);
        }
    };

    stage(0, 0);
    asm volatile("s_waitcnt vmcnt(0)" ::: "memory");
    __syncthreads();

    for (int chunk = 0; chunk < HIDD / KC; ++chunk) {
        const int buf = chunk & 1;
        if (chunk + 1 < HIDD / KC) stage(chunk + 1, buf ^ 1);

        const float* wc  = weff + chunk * KC;
        const float* shl = &sh[buf][lane * KC];
#pragma unroll
        for (int kc = 0; kc < KC / 4; ++kc) {
            // slot (lane, kc^swz) contains source f4-col kc of row `lane`
            float4 h4 = *reinterpret_cast<const float4*>(shl + ((kc ^ swz) << 2));
#pragma unroll
            for (int o = 0; o < 4; ++o) {
                // wave-uniform address -> s_load through scalar cache
                float4 wv = *reinterpret_cast<const float4*>(
                    wc + (size_t)(obase + o) * HIDD + kc * 4);
                acc[o] += h4.x * wv.x + h4.y * wv.y + h4.z * wv.z + h4.w * wv.w;
            }
        }
        asm volatile("s_waitcnt vmcnt(0)" ::: "memory");
        __syncthreads();      // next buf ready; current buf free to restage
    }

    float m = mask[row];               // mask is (B,1,1,S) = flat 32768
#pragma unroll
    for (int o = 0; o < 4; ++o) acc[o] *= m;

    float4 v = make_float4(acc[0], acc[1], acc[2], acc[3]);
    if (obase < 16) {
        *reinterpret_cast<float4*>(qsb + (size_t)row * 16 + obase) = v;
    } else {
        *reinterpret_cast<float4*>(ksb + (size_t)row * 20 + (obase - 16)) = v;
        if (obase == 16) ksb[(size_t)row * 20 + 16] = m;
    }
}

// K3 v3: NO atomics. Thread owns 4 cols (float4 loads, 68 accumulators),
// s-chunk 64 rows -> grid (64, 8) = 512 blocks = 2/CU.
// part[schunk][b][17][1024]: ksh partial (16 ch) + hsum partial (mask ch).
__global__ __launch_bounds__(256) void k_ksh(const float* __restrict__ hid,
                                             const float* __restrict__ ksb,
                                             float* __restrict__ part) {
    int b  = blockIdx.y;
    int i  = threadIdx.x * 4;
    int s0 = blockIdx.x * 64;

    float4 acc[17];
#pragma unroll
    for (int c = 0; c < 17; ++c) acc[c] = make_float4(0.f, 0.f, 0.f, 0.f);

    const float* hb = hid + (size_t)(b * SS + s0) * HIDD + i;
    const float* sb = ksb + (size_t)(b * SS + s0) * 20;

#pragma unroll 4
    for (int s = 0; s < 64; ++s) {
        float4 hv = *reinterpret_cast<const float4*>(hb + (size_t)s * HIDD);
        const float* sc = sb + s * 20;
#pragma unroll
        for (int c = 0; c < 17; ++c) {
            float scv = sc[c];
            acc[c].x += scv * hv.x;
            acc[c].y += scv * hv.y;
            acc[c].z += scv * hv.z;
            acc[c].w += scv * hv.w;
        }
    }

    float* pb = part + (((size_t)blockIdx.x * 8 + b) * 17) * 1024 + i;
#pragma unroll
    for (int c = 0; c < 17; ++c) {
        *reinterpret_cast<float4*>(pb + c * 1024) = acc[c];
    }
}

// K3b: reduce 64 schunk partials -> ksh[b][16][1024], hsum[b][1024].
// grid 544, block 256 (544*256 = 8*17*1024 outputs exactly)
__global__ __launch_bounds__(256) void k_red(const float* __restrict__ part,
                                             float* __restrict__ ksh,
                                             float* __restrict__ hsum) {
    int gid = blockIdx.x * 256 + threadIdx.x;
    int b = gid / 17408;               // 17*1024
    int r = gid - b * 17408;
    int c = r >> 10;
    int i = r & 1023;

    float s = 0.f;
#pragma unroll 8
    for (int k = 0; k < 64; ++k)
        s += part[(((size_t)k * 8 + b) * 17 + c) * 1024 + i];

    if (c < 16) ksh[((size_t)b * 16 + c) * 1024 + i] = s;
    else        hsum[b * 1024 + i] = s;
}

// K4 v2: mvn[b,j] = (Wv[j,:]·hsum[b,:])/len;  kvn[b,j] = (Wv[j,:]·ksh[b,j/64,:])/len
// grid (8, 32), block 256: 32 j per block, 8 lanes split each 1024-dot,
// __shfl_xor reduce over the 8-lane group.
__global__ __launch_bounds__(256) void k_fin(const float* __restrict__ Wv,
                                             const float* __restrict__ mask,
                                             const float* __restrict__ hsum,
                                             const float* __restrict__ ksh,
                                             float* __restrict__ mvn,
                                             float* __restrict__ kvn) {
    int b  = blockIdx.x;
    int j  = blockIdx.y * 32 + (threadIdx.x >> 3);
    int sl = threadIdx.x & 7;

    __shared__ float red[256];
    float lsum = 0.f;
    for (int s = threadIdx.x; s < SS; s += 256) lsum += mask[b * SS + s];
    red[threadIdx.x] = lsum;
    __syncthreads();
    for (int off = 128; off; off >>= 1) {
        if (threadIdx.x < off) red[threadIdx.x] += red[threadIdx.x + off];
        __syncthreads();
    }
    float invlen = 1.0f / red[0];

    int h = j >> 6;
    const float4* w4 = reinterpret_cast<const float4*>(Wv + (size_t)j * HIDD + sl * 128);
    const float4* hv = reinterpret_cast<const float4*>(hsum + b * HIDD + sl * 128);
    const float4* kv = reinterpret_cast<const float4*>(ksh + ((size_t)b * 16 + h) * HIDD + sl * 128);

    float mv = 0.f, kvv = 0.f;
#pragma unroll
    for (int c = 0; c < 32; ++c) {
        float4 w = w4[c], a = hv[c], k2 = kv[c];
        mv  += w.x * a.x  + w.y * a.y  + w.z * a.z  + w.w * a.w;
        kvv += w.x * k2.x + w.y * k2.y + w.z * k2.z + w.w * k2.w;
    }
#pragma unroll
    for (int off = 1; off < 8; off <<= 1) {
        mv  += __shfl_xor(mv, off);
        kvv += __shfl_xor(kvv, off);
    }
    if (sl == 0) {
        mvn[b * HIDD + j] = mv * invlen;
        kvn[b * HIDD + j] = kvv * invlen;
    }
}

// K5: out[b,s,j] = q_score[b,s,j/64]*mvn[b,j] + kvn[b,j], float4 stores.
// grid 16384, block 256, 8 elems/thread
__global__ __launch_bounds__(256) void k_out(const float* __restrict__ qsb,
                                             const float* __restrict__ mvn,
                                             const float* __restrict__ kvn,
                                             float* __restrict__ outp) {
    size_t e0 = ((size_t)blockIdx.x * 256 + threadIdx.x) * 8;
    int b   = (int)(e0 >> 22);                 // 4096*1024 = 2^22
    int rem = (int)(e0 & ((1u << 22) - 1));
    int s   = rem >> 10;
    int j   = rem & 1023;

    float q = qsb[(size_t)(b * SS + s) * 16 + (j >> 6)];
    const float4* mv4 = reinterpret_cast<const float4*>(mvn + b * HIDD + j);
    const float4* kv4 = reinterpret_cast<const float4*>(kvn + b * HIDD + j);
    float4 m0 = mv4[0], m1 = mv4[1];
    float4 k0 = kv4[0], k1 = kv4[1];

    float4 o0, o1;
    o0.x = q * m0.x + k0.x;  o0.y = q * m0.y + k0.y;
    o0.z = q * m0.z + k0.z;  o0.w = q * m0.w + k0.w;
    o1.x = q * m1.x + k1.x;  o1.y = q * m1.y + k1.y;
    o1.z = q * m1.z + k1.z;  o1.w = q * m1.w + k1.w;

    float4* op = reinterpret_cast<float4*>(outp + e0);
    op[0] = o0;
    op[1] = o1;
}

extern "C" void kernel_launch(void* const* d_in, const int* in_sizes, int n_in,
                              void* d_out, int out_size, void* d_ws, size_t ws_size,
                              hipStream_t stream) {
    const float* hid  = (const float*)d_in[0];   // (B,S,HID)
    const float* mask = (const float*)d_in[1];   // (B,1,1,S)
    const float* Wq   = (const float*)d_in[2];   // (HID,HID)
    const float* Wk   = (const float*)d_in[3];
    const float* Wv   = (const float*)d_in[4];
    const float* aw   = (const float*)d_in[5];   // (H,1,DH)
    float* outp = (float*)d_out;

    float* ws   = (float*)d_ws;
    float* wq_f = ws;                       // 16384   } weff[32][1024]
    float* wk_f = wq_f + 16384;             // 16384   } (adjacent)
    float* qsb  = wk_f + 16384;             // 8*4096*16 = 524288
    float* ksb  = qsb + 524288;             // 8*4096*20 = 655360
    float* ksh  = ksb + 655360;             // 8*16*1024 = 131072
    float* hsum = ksh + 131072;             // 8*1024   = 8192
    float* mvn  = hsum + 8192;              // 8192
    float* kvn  = mvn + 8192;               // 8192
    float* part = kvn + 8192;               // 64*8*17*1024 = 8912896 (~35.7 MB)

    k_prep  <<<dim3(4, 16, 2), 256, 0, stream>>>(Wq, Wk, aw, wq_f, wk_f);
    k_scores<<<dim3(512),      512, 0, stream>>>(hid, mask, wq_f, qsb, ksb);
    k_ksh   <<<dim3(64, 8),    256, 0, stream>>>(hid, ksb, part);
    k_red   <<<dim3(544),      256, 0, stream>>>(part, ksh, hsum);
    k_fin   <<<dim3(8, 32),    256, 0, stream>>>(Wv, mask, hsum, ksh, mvn, kvn);
    k_out   <<<dim3(16384),    256, 0, stream>>>(qsb, mvn, kvn, outp);
}

// Round 4
// 343.422 us; speedup vs baseline: 1.2482x; 1.0212x over previous
//
#include <hip/hip_runtime.h>

#define BB 8
#define SS 4096
#define HIDD 1024
#define HH 16
#define DHH 64

// K1: weff[o][i], o<16: sum_d aw[o,d]*Wq[o*64+d, i]; o>=16: same with Wk.
// wq_f and wk_f are adjacent in ws => weff = wq_f is [32][1024].
// grid (4, 16, 2), block 256
__global__ __launch_bounds__(256) void k_prep(const float* __restrict__ Wq,
                                              const float* __restrict__ Wk,
                                              const float* __restrict__ aw,
                                              float* __restrict__ wq_f,
                                              float* __restrict__ wk_f) {
    int i = blockIdx.x * 256 + threadIdx.x;
    int h = blockIdx.y;
    const float* W = blockIdx.z ? Wk : Wq;
    float* outp = blockIdx.z ? wk_f : wq_f;
    float acc = 0.f;
#pragma unroll
    for (int d = 0; d < DHH; ++d) {
        acc += aw[h * DHH + d] * W[(size_t)(h * DHH + d) * HIDD + i];
    }
    outp[h * HIDD + i] = acc;
}

// K2 v7: tall-skinny GEMM  scores[32768 rows][32 outs] = hid x weff^T.
// Round-3 lesson: wave-uniform weight reads became s_load (SMEM); SMEM+DS
// share lgkmcnt and SMEM retires out-of-order => compiler must lgkmcnt(0)
// full-drain every few k-steps => VALUBusy 24%. Fix: stage the WEIGHT chunk
// in LDS too -> inner loop is all-DS -> fine-grained counted lgkmcnt.
// KC=64, dbuf: shh[2][64*64] (32KB) + shw[2][32*64] (16KB) = 48KB
// -> 3 blocks/CU = 24 waves/CU. Block 512 thr = 8 waves, wave owns 4 outs,
// lane = row. Staging via global_load_lds w16 (3 loads/thread/chunk).
// Hid swizzle (rule #21): slot (r,cp) holds source f4-col cp^(r&7); read
// col kc^(lane&7) -> per-phase 8 lanes spread over all 8 4-bank groups.
// Weight reads are wave-uniform ds_read_b128 = broadcast, conflict-free.
#define KC 64
#define NCH (HIDD / KC)
__global__ __launch_bounds__(512) void k_scores(const float* __restrict__ hid,
                                                const float* __restrict__ mask,
                                                const float* __restrict__ weff,
                                                float* __restrict__ qsb,
                                                float* __restrict__ ksb) {
    __shared__ float shh[2][64 * KC];     // 2 x 16 KB
    __shared__ float shw[2][32 * KC];     // 2 x  8 KB

    const int t    = threadIdx.x;         // 0..511
    const int lane = t & 63;
    const int wave = t >> 6;              // 0..7
    const int obase = __builtin_amdgcn_readfirstlane(wave * 4);  // 0..28

    const int row  = blockIdx.x * 64 + lane;        // global row (b*4096+s)
    const size_t gbase = (size_t)blockIdx.x * 64 * HIDD;
    const int swz = lane & 7;

    float acc[4] = {0.f, 0.f, 0.f, 0.f};

    // hid chunk: 64 rows x 16 f4-cols = 1024 slots, 2/thread (source-swizzled).
    // weight chunk: 32 outs x 16 f4-cols = 512 slots, 1/thread (linear).
    auto stage = [&](int chunk, int buf) {
#pragma unroll
        for (int j = 0; j < 2; ++j) {
            int f  = j * 512 + t;
            int r  = f >> 4;               // 16 f4 per row
            int cp = f & 15;
            int c  = cp ^ (r & 7);
            const float* gp = hid + gbase + (size_t)r * HIDD + chunk * KC + c * 4;
            float* lp = &shh[buf][f * 4];
            __builtin_amdgcn_global_load_lds(
                (const __attribute__((address_space(1))) void*)gp,
                (__attribute__((address_space(3))) void*)lp, 16, 0, 0);
        }
        {
            int o  = t >> 4;               // 0..31
            int cp = t & 15;
            const float* gp = weff + (size_t)o * HIDD + chunk * KC + cp * 4;
            float* lp = &shw[buf][t * 4];
            __builtin_amdgcn_global_load_lds(
                (const __attribute__((address_space(1))) void*)gp,
                (__attribute__((address_space(3))) void*)lp, 16, 0, 0);
        }
    };

    stage(0, 0);

    for (int chunk = 0; chunk < NCH; ++chunk) {
        const int buf = chunk & 1;
        asm volatile("s_waitcnt vmcnt(0)" ::: "memory");  // own stage(chunk) done
        __syncthreads();                                  // all waves off buf^1
        if (chunk + 1 < NCH) stage(chunk + 1, buf ^ 1);   // prefetch under compute

        const float* hb = &shh[buf][lane * KC];
        const float* wb = &shw[buf][0];
#pragma unroll
        for (int kc = 0; kc < KC / 4; ++kc) {
            float4 h4 = *reinterpret_cast<const float4*>(hb + ((kc ^ swz) << 2));
#pragma unroll
            for (int o = 0; o < 4; ++o) {
                float4 wv = *reinterpret_cast<const float4*>(
                    wb + (obase + o) * KC + (kc << 2));
                acc[o] += h4.x * wv.x + h4.y * wv.y + h4.z * wv.z + h4.w * wv.w;
            }
        }
    }

    float m = mask[row];               // mask is (B,1,1,S) = flat 32768
#pragma unroll
    for (int o = 0; o < 4; ++o) acc[o] *= m;

    float4 v = make_float4(acc[0], acc[1], acc[2], acc[3]);
    if (obase < 16) {
        *reinterpret_cast<float4*>(qsb + (size_t)row * 16 + obase) = v;
    } else {
        *reinterpret_cast<float4*>(ksb + (size_t)row * 20 + (obase - 16)) = v;
        if (obase == 16) ksb[(size_t)row * 20 + 16] = m;
    }
}

// K3 v3: NO atomics. Thread owns 4 cols (float4 loads, 68 accumulators),
// s-chunk 64 rows -> grid (64, 8) = 512 blocks = 2/CU.
// part[schunk][b][17][1024]: ksh partial (16 ch) + hsum partial (mask ch).
__global__ __launch_bounds__(256) void k_ksh(const float* __restrict__ hid,
                                             const float* __restrict__ ksb,
                                             float* __restrict__ part) {
    int b  = blockIdx.y;
    int i  = threadIdx.x * 4;
    int s0 = blockIdx.x * 64;

    float4 acc[17];
#pragma unroll
    for (int c = 0; c < 17; ++c) acc[c] = make_float4(0.f, 0.f, 0.f, 0.f);

    const float* hb = hid + (size_t)(b * SS + s0) * HIDD + i;
    const float* sb = ksb + (size_t)(b * SS + s0) * 20;

#pragma unroll 4
    for (int s = 0; s < 64; ++s) {
        float4 hv = *reinterpret_cast<const float4*>(hb + (size_t)s * HIDD);
        const float* sc = sb + s * 20;
#pragma unroll
        for (int c = 0; c < 17; ++c) {
            float scv = sc[c];
            acc[c].x += scv * hv.x;
            acc[c].y += scv * hv.y;
            acc[c].z += scv * hv.z;
            acc[c].w += scv * hv.w;
        }
    }

    float* pb = part + (((size_t)blockIdx.x * 8 + b) * 17) * 1024 + i;
#pragma unroll
    for (int c = 0; c < 17; ++c) {
        *reinterpret_cast<float4*>(pb + c * 1024) = acc[c];
    }
}

// K3b: reduce 64 schunk partials -> ksh[b][16][1024], hsum[b][1024].
// grid 544, block 256 (544*256 = 8*17*1024 outputs exactly)
__global__ __launch_bounds__(256) void k_red(const float* __restrict__ part,
                                             float* __restrict__ ksh,
                                             float* __restrict__ hsum) {
    int gid = blockIdx.x * 256 + threadIdx.x;
    int b = gid / 17408;               // 17*1024
    int r = gid - b * 17408;
    int c = r >> 10;
    int i = r & 1023;

    float s = 0.f;
#pragma unroll 8
    for (int k = 0; k < 64; ++k)
        s += part[(((size_t)k * 8 + b) * 17 + c) * 1024 + i];

    if (c < 16) ksh[((size_t)b * 16 + c) * 1024 + i] = s;
    else        hsum[b * 1024 + i] = s;
}

// K4 v2: mvn[b,j] = (Wv[j,:]·hsum[b,:])/len;  kvn[b,j] = (Wv[j,:]·ksh[b,j/64,:])/len
// grid (8, 32), block 256: 32 j per block, 8 lanes split each 1024-dot,
// __shfl_xor reduce over the 8-lane group.
__global__ __launch_bounds__(256) void k_fin(const float* __restrict__ Wv,
                                             const float* __restrict__ mask,
                                             const float* __restrict__ hsum,
                                             const float* __restrict__ ksh,
                                             float* __restrict__ mvn,
                                             float* __restrict__ kvn) {
    int b  = blockIdx.x;
    int j  = blockIdx.y * 32 + (threadIdx.x >> 3);
    int sl = threadIdx.x & 7;

    __shared__ float red[256];
    float lsum = 0.f;
    for (int s = threadIdx.x; s < SS; s += 256) lsum += mask[b * SS + s];
    red[threadIdx.x] = lsum;
    __syncthreads();
    for (int off = 128; off; off >>= 1) {
        if (threadIdx.x < off) red[threadIdx.x] += red[threadIdx.x + off];
        __syncthreads();
    }
    float invlen = 1.0f / red[0];

    int h = j >> 6;
    const float4* w4 = reinterpret_cast<const float4*>(Wv + (size_t)j * HIDD + sl * 128);
    const float4* hv = reinterpret_cast<const float4*>(hsum + b * HIDD + sl * 128);
    const float4* kv = reinterpret_cast<const float4*>(ksh + ((size_t)b * 16 + h) * HIDD + sl * 128);

    float mv = 0.f, kvv = 0.f;
#pragma unroll
    for (int c = 0; c < 32; ++c) {
        float4 w = w4[c], a = hv[c], k2 = kv[c];
        mv  += w.x * a.x  + w.y * a.y  + w.z * a.z  + w.w * a.w;
        kvv += w.x * k2.x + w.y * k2.y + w.z * k2.z + w.w * k2.w;
    }
#pragma unroll
    for (int off = 1; off < 8; off <<= 1) {
        mv  += __shfl_xor(mv, off);
        kvv += __shfl_xor(kvv, off);
    }
    if (sl == 0) {
        mvn[b * HIDD + j] = mv * invlen;
        kvn[b * HIDD + j] = kvv * invlen;
    }
}

// K5: out[b,s,j] = q_score[b,s,j/64]*mvn[b,j] + kvn[b,j], float4 stores.
// grid 16384, block 256, 8 elems/thread
__global__ __launch_bounds__(256) void k_out(const float* __restrict__ qsb,
                                             const float* __restrict__ mvn,
                                             const float* __restrict__ kvn,
                                             float* __restrict__ outp) {
    size_t e0 = ((size_t)blockIdx.x * 256 + threadIdx.x) * 8;
    int b   = (int)(e0 >> 22);                 // 4096*1024 = 2^22
    int rem = (int)(e0 & ((1u << 22) - 1));
    int s   = rem >> 10;
    int j   = rem & 1023;

    float q = qsb[(size_t)(b * SS + s) * 16 + (j >> 6)];
    const float4* mv4 = reinterpret_cast<const float4*>(mvn + b * HIDD + j);
    const float4* kv4 = reinterpret_cast<const float4*>(kvn + b * HIDD + j);
    float4 m0 = mv4[0], m1 = mv4[1];
    float4 k0 = kv4[0], k1 = kv4[1];

    float4 o0, o1;
    o0.x = q * m0.x + k0.x;  o0.y = q * m0.y + k0.y;
    o0.z = q * m0.z + k0.z;  o0.w = q * m0.w + k0.w;
    o1.x = q * m1.x + k1.x;  o1.y = q * m1.y + k1.y;
    o1.z = q * m1.z + k1.z;  o1.w = q * m1.w + k1.w;

    float4* op = reinterpret_cast<float4*>(outp + e0);
    op[0] = o0;
    op[1] = o1;
}

extern "C" void kernel_launch(void* const* d_in, const int* in_sizes, int n_in,
                              void* d_out, int out_size, void* d_ws, size_t ws_size,
                              hipStream_t stream) {
    const float* hid  = (const float*)d_in[0];   // (B,S,HID)
    const float* mask = (const float*)d_in[1];   // (B,1,1,S)
    const float* Wq   = (const float*)d_in[2];   // (HID,HID)
    const float* Wk   = (const float*)d_in[3];
    const float* Wv   = (const float*)d_in[4];
    const float* aw   = (const float*)d_in[5];   // (H,1,DH)
    float* outp = (float*)d_out;

    float* ws   = (float*)d_ws;
    float* wq_f = ws;                       // 16384   } weff[32][1024]
    float* wk_f = wq_f + 16384;             // 16384   } (adjacent)
    float* qsb  = wk_f + 16384;             // 8*4096*16 = 524288
    float* ksb  = qsb + 524288;             // 8*4096*20 = 655360
    float* ksh  = ksb + 655360;             // 8*16*1024 = 131072
    float* hsum = ksh + 131072;             // 8*1024   = 8192
    float* mvn  = hsum + 8192;              // 8192
    float* kvn  = mvn + 8192;               // 8192
    float* part = kvn + 8192;               // 64*8*17*1024 = 8912896 (~35.7 MB)

    k_prep  <<<dim3(4, 16, 2), 256, 0, stream>>>(Wq, Wk, aw, wq_f, wk_f);
    k_scores<<<dim3(512),      512, 0, stream>>>(hid, mask, wq_f, qsb, ksb);
    k_ksh   <<<dim3(64, 8),    256, 0, stream>>>(hid, ksb, part);
    k_red   <<<dim3(544),      256, 0, stream>>>(part, ksh, hsum);
    k_fin   <<<dim3(8, 32),    256, 0, stream>>>(Wv, mask, hsum, ksh, mvn, kvn);
    k_out   <<<dim3(16384),    256, 0, stream>>>(qsb, mvn, kvn, outp);
}